// Round 4
// baseline (47.548 us; speedup 1.0000x reference)
//
#include <hip/hip_runtime.h>
#include <hip/hip_bf16.h>

// Problem: B=16384, I=512, H=512.
// Output = modrelu(complex(inputs@w_ih.T [:, :512], [:, 512:]), b_h)
// The FFT/reflect/perm state path in the reference is DEAD CODE (preact unused).
//
// Single fused GEMM: A is read as f32 and converted to bf16 in-register
// (T14 reg-staging, swizzled ds_write). W (2 MB) is pre-converted once.

typedef __attribute__((ext_vector_type(8))) short bf16x8;
typedef __attribute__((ext_vector_type(4))) float f32x4;

#define BM 256            // M rows per block
#define BK 64             // K per tile
#define KDIM 512
#define NDIM 1024
#define NKT (KDIM / BK)   // 8 K-tiles

__device__ __forceinline__ unsigned short f2bf(float f) {
    unsigned u = __builtin_bit_cast(unsigned, f);
    u += 0x7fffu + ((u >> 16) & 1u);   // round-to-nearest-even
    return (unsigned short)(u >> 16);
}

__global__ __launch_bounds__(256) void cvt_w(const float* __restrict__ W,
                                             unsigned short* __restrict__ Wbf, int n4) {
    int i = blockIdx.x * blockDim.x + threadIdx.x;
    int stride = gridDim.x * blockDim.x;
    for (; i < n4; i += stride) {
        float4 v = reinterpret_cast<const float4*>(W)[i];
        ushort4 o;
        o.x = f2bf(v.x); o.y = f2bf(v.y); o.z = f2bf(v.z); o.w = f2bf(v.w);
        reinterpret_cast<ushort4*>(Wbf)[i] = o;
    }
}

__device__ __forceinline__ void gload_lds16(const void* g, void* l) {
    __builtin_amdgcn_global_load_lds(
        (const __attribute__((address_space(1))) unsigned int*)g,
        (__attribute__((address_space(3))) unsigned int*)l, 16, 0, 0);
}

// 256x256 tile (256 M-rows x 128 re/im col-pairs), 8 waves in 2M x 4N grid.
// A: f32 -> regs -> bf16 -> swizzled ds_write (8 dwordx4 + 8 ds_write_b64 /thread/tile)
// B: bf16 global_load_lds with pre-swizzled source (4 issues /thread/tile)
// Counted-vmcnt pipeline: steady state keeps 12 vmem ops in flight, never vmcnt(0).
__global__ __launch_bounds__(512, 2) void gemm_modrelu(
    const float* __restrict__ A,            // 16384 x 512 f32
    const unsigned short* __restrict__ W,   // 1024 x 512 bf16 (pre-converted)
    const float* __restrict__ bh,           // 512 f32
    float* __restrict__ out)                // 16384 x 1024 f32
{
    __shared__ unsigned short At[2][BM * BK];  // 2 x 32 KiB
    __shared__ unsigned short Bt[2][BM * BK];  // 2 x 32 KiB (128 KiB total)

    const int tid = threadIdx.x;
    const int w   = tid >> 6;
    const int l   = tid & 63;
    const int l15 = l & 15;
    const int l4  = l >> 4;
    const int wm  = w >> 2;        // 0..1 : M half (128 rows)
    const int wn  = w & 3;         // 0..3 : 32 col-pairs

    // T1: XCD-chunked swizzle (256 blocks, 8 XCDs, 32/XCD).
    const int bx = blockIdx.x;
    const int lg = (bx & 7) * 32 + (bx >> 3);
    const int mb = lg >> 2;        // 64 m-blocks of 256 rows
    const int cb = lg & 3;         // 4 col-blocks of 128 pairs

    // ---- A staging (f32 -> reg -> bf16 -> LDS, both-sides swizzle) ----
    // sweep s: row = s*32 + (tid>>4), 16B f32 seg = tid&15 (coalesced: 16 lanes/row)
    const int arow0 = tid >> 4;          // 0..31
    const int aseg  = tid & 15;          // 0..15
    const int aswz  = (arow0 & 7) << 3;  // swizzle in shorts (row&7 is sweep-invariant)
    const float4* ga[8];
#pragma unroll
    for (int s = 0; s < 8; ++s)
        ga[s] = reinterpret_cast<const float4*>(
                    A + (size_t)(mb * BM + s * 32 + arow0) * KDIM) + aseg;

    // ---- B staging (gload_lds, pre-swizzled source) ----
    const int srow = l >> 3;
    const int sseg = (l & 7) ^ srow;
    const unsigned short* gb[4];
    int ldso[4];
#pragma unroll
    for (int is = 0; is < 4; ++is) {
        int row  = w * 32 + is * 8 + srow;
        int wrow = (row >> 7) * 512 + cb * 128 + (row & 127);  // re rows then im rows
        gb[is]   = W + (size_t)wrow * KDIM + sseg * 8;
        ldso[is] = (w * 32 + is * 8) * BK;                      // wave-uniform LDS base
    }

    float4 ra[8];
    auto load_a = [&](int kt) {
#pragma unroll
        for (int s = 0; s < 8; ++s) ra[s] = ga[s][kt * (BK / 4)];
    };
    auto write_a = [&](int buf) {
#pragma unroll
        for (int s = 0; s < 8; ++s) {
            ushort4 o;
            o.x = f2bf(ra[s].x); o.y = f2bf(ra[s].y);
            o.z = f2bf(ra[s].z); o.w = f2bf(ra[s].w);
            int row = s * 32 + arow0;
            *reinterpret_cast<ushort4*>(&At[buf][row * BK + ((aseg * 4) ^ aswz)]) = o;
        }
    };
    auto stage_b = [&](int kt, int buf) {
#pragma unroll
        for (int is = 0; is < 4; ++is)
            gload_lds16(gb[is] + kt * BK, &Bt[buf][ldso[is]]);
    };

    f32x4 acc[8][4];
#pragma unroll
    for (int i = 0; i < 8; ++i)
#pragma unroll
        for (int j = 0; j < 4; ++j) acc[i][j] = f32x4{0.f, 0.f, 0.f, 0.f};

    // ---- prologue: tile0 in LDS, tile1 in flight ----
    load_a(0);
    asm volatile("s_waitcnt vmcnt(0)" ::: "memory");
    write_a(0);
    stage_b(0, 0);                                   // 4 out (oldest)
    load_a(1);                                       // +8 = 12
    stage_b(1, 1);                                   // +4 = 16
    asm volatile("s_waitcnt vmcnt(12) lgkmcnt(0)" ::: "memory");  // B0 + A0-writes done
    __builtin_amdgcn_s_barrier();

#pragma unroll
    for (int kt = 0; kt < NKT; ++kt) {
        const int buf = kt & 1;

        // (1)(2) A(kt+1): regs ready -> convert + swizzled write to buf^1
        if (kt + 1 < NKT) {
            asm volatile("s_waitcnt vmcnt(4)" ::: "memory");  // drain A(kt+1), keep B(kt+1)
            write_a(buf ^ 1);
        }
        // (3) issue A(kt+2) f32 loads (in flight across this tile's compute)
        if (kt + 2 < NKT) load_a(kt + 2);

        // (4) compute tile kt
#pragma unroll
        for (int ks = 0; ks < 2; ++ks) {
            bf16x8 af[8], bf[4];
            const int slot = (ks * 4 + l4);
#pragma unroll
            for (int i = 0; i < 8; ++i) {
                int row = wm * 128 + i * 16 + l15;
                af[i] = *(const bf16x8*)(&At[buf][row * BK + (slot ^ (row & 7)) * 8]);
            }
#pragma unroll
            for (int jn = 0; jn < 4; ++jn) {
                int row = (jn < 2) ? (wn * 32 + jn * 16 + l15)
                                   : (128 + wn * 32 + (jn - 2) * 16 + l15);
                bf[jn] = *(const bf16x8*)(&Bt[buf][row * BK + (slot ^ (row & 7)) * 8]);
            }
            asm volatile("s_waitcnt lgkmcnt(0)" ::: "memory");
            __builtin_amdgcn_sched_barrier(0);
            __builtin_amdgcn_s_setprio(1);
#pragma unroll
            for (int i = 0; i < 8; ++i)
#pragma unroll
                for (int jn = 0; jn < 4; ++jn)
                    acc[i][jn] = __builtin_amdgcn_mfma_f32_16x16x32_bf16(
                        af[i], bf[jn], acc[i][jn], 0, 0, 0);
            __builtin_amdgcn_s_setprio(0);
        }

        if (kt + 1 < NKT) {
            __builtin_amdgcn_s_barrier();   // (5) all done reading buf / writing buf^1
            // (6) B(kt+1) landed (oldest in flight); keep A(kt+2)'s 8 in flight
            if (kt + 2 < NKT) asm volatile("s_waitcnt vmcnt(8)" ::: "memory");
            else              asm volatile("s_waitcnt vmcnt(0)" ::: "memory");
            // (7) B(kt+2) -> buf (safe: everyone done reading buf)
            if (kt + 2 < NKT) stage_b(kt + 2, buf);
            __builtin_amdgcn_s_barrier();   // (8) tile kt+1 fully visible
        }
    }

    // ---- fused modReLU epilogue ----
    // C/D layout (m89): col = lane&15 (n), row = (lane>>4)*4 + j (m)
#pragma unroll
    for (int jn = 0; jn < 2; ++jn) {
        int n = cb * 128 + wn * 32 + jn * 16 + l15;
        float b = bh[n];
#pragma unroll
        for (int i = 0; i < 8; ++i) {
#pragma unroll
            for (int j = 0; j < 4; ++j) {
                int m = mb * BM + wm * 128 + i * 16 + l4 * 4 + j;
                float re  = acc[i][jn][j];
                float imv = acc[i][jn + 2][j];
                float norm  = sqrtf(re * re + imv * imv);
                float scale = fmaxf(norm + b, 0.f) * __builtin_amdgcn_rcpf(norm + 1e-6f);
                float* po = out + (size_t)m * NDIM + n;
                __builtin_nontemporal_store(re  * scale, po);
                __builtin_nontemporal_store(imv * scale, po + 512);
            }
        }
    }
}

extern "C" void kernel_launch(void* const* d_in, const int* in_sizes, int n_in,
                              void* d_out, int out_size, void* d_ws, size_t ws_size,
                              hipStream_t stream) {
    const float* inputs = (const float*)d_in[0];   // (16384, 512) f32
    const float* w_ih   = (const float*)d_in[2];   // (1024, 512)  f32
    const float* b_h    = (const float*)d_in[3];   // (512,)       f32
    float* out = (float*)d_out;                    // (16384, 1024) f32

    unsigned short* Wbf = (unsigned short*)d_ws;   // 1 MiB

    cvt_w<<<512, 256, 0, stream>>>(w_ih, Wbf, (1024 * 512) / 4);

    // fused GEMM + modReLU: 64 m-blocks x 4 col-blocks = 256 blocks (1/CU)
    gemm_modrelu<<<256, 512, 0, stream>>>(inputs, Wbf, b_h, out);
}

// Round 5
// 41.574 us; speedup vs baseline: 1.1437x; 1.1437x over previous
//
#include <hip/hip_runtime.h>
#include <hip/hip_bf16.h>

// Problem: B=16384, I=512, H=512.
// Output = modrelu(complex(inputs@w_ih.T [:, :512], [:, 512:]), b_h)
// The FFT/reflect/perm state path in the reference is DEAD CODE (preact unused).
//
// Fused GEMM: A read as f32, converted in-register (v_cvt_pk_bf16_f32),
// swizzled ds_write. W (2 MB) pre-converted. 128x128 tiles, 2 blocks/CU,
// 3-deep A prefetch, counted vmcnt(8) steady state.

typedef __attribute__((ext_vector_type(8))) short bf16x8;
typedef __attribute__((ext_vector_type(4))) float f32x4;

#define BM 128            // M rows per block
#define BK 64             // K per tile
#define KDIM 512
#define NDIM 1024
#define NKT 8

#define VMCNT(n) asm volatile("s_waitcnt vmcnt(" #n ")" ::: "memory")
#define LGKM(n)  asm volatile("s_waitcnt lgkmcnt(" #n ")" ::: "memory")

__device__ __forceinline__ unsigned short f2bf(float f) {
    unsigned u = __builtin_bit_cast(unsigned, f);
    u += 0x7fffu + ((u >> 16) & 1u);
    return (unsigned short)(u >> 16);
}

__global__ __launch_bounds__(256) void cvt_w(const float* __restrict__ W,
                                             unsigned short* __restrict__ Wbf, int n4) {
    int i = blockIdx.x * blockDim.x + threadIdx.x;
    int stride = gridDim.x * blockDim.x;
    for (; i < n4; i += stride) {
        float4 v = reinterpret_cast<const float4*>(W)[i];
        ushort4 o;
        o.x = f2bf(v.x); o.y = f2bf(v.y); o.z = f2bf(v.z); o.w = f2bf(v.w);
        reinterpret_cast<ushort4*>(Wbf)[i] = o;
    }
}

__device__ __forceinline__ void gload_lds16(const void* g, void* l) {
    __builtin_amdgcn_global_load_lds(
        (const __attribute__((address_space(1))) unsigned int*)g,
        (__attribute__((address_space(3))) unsigned int*)l, 16, 0, 0);
}

__device__ __forceinline__ unsigned cvtpk(float lo, float hi) {
    unsigned r;
    asm("v_cvt_pk_bf16_f32 %0, %1, %2" : "=v"(r) : "v"(lo), "v"(hi));
    return r;
}

// 128 M-rows x 64 re/im col-pairs per block. 4 waves, 2M x 2N; per wave
// 64 rows x 32 pairs = acc[4][4] (j 0..1 re, 2..3 im).
// B-tile rows 0..63 = W[cb*64+r] (re), 64..127 = W[512+cb*64+r] (im).
__global__ __launch_bounds__(256, 2) void gemm_modrelu(
    const float* __restrict__ A,            // 16384 x 512 f32
    const unsigned short* __restrict__ W,   // 1024 x 512 bf16
    const float* __restrict__ bh,           // 512 f32
    float* __restrict__ out)                // 16384 x 1024 f32
{
    __shared__ unsigned short At[2][BM * BK];  // 2 x 16 KiB
    __shared__ unsigned short Bt[2][BM * BK];  // 2 x 16 KiB  (64 KiB -> 2 blocks/CU)

    const int tid = threadIdx.x;
    const int w   = tid >> 6;
    const int l   = tid & 63;
    const int l15 = l & 15;
    const int l4  = l >> 4;
    const int wm  = w >> 1;        // 0..1 : 64-row half
    const int wn  = w & 1;         // 0..1 : 32-pair half

    // T1: XCD-chunked swizzle. 1024 blocks, 128/XCD; cb fastest -> the 8
    // sharers of each A panel run on one XCD (1 HBM fetch + 7 L2 hits).
    const int bx = blockIdx.x;
    const int lg = (bx & 7) * 128 + (bx >> 3);
    const int mb = lg >> 3;        // 128 m-blocks of 128 rows
    const int cb = lg & 7;         // 8 col-blocks of 64 pairs

    // ---- A staging (f32 -> reg -> bf16 -> swizzled LDS) ----
    // 8 sweeps: row = s*16 + (tid>>4); 16B f32 seg = tid&15.
    const int arow0 = tid >> 4;          // 0..15
    const int aseg  = tid & 15;          // 0..15
    const int aswz  = (arow0 & 7) << 3;  // swizzle (slot-granular, in shorts)
    const float4* gA = reinterpret_cast<const float4*>(A) + (size_t)(mb * BM) * (KDIM / 4);
    const int abase = arow0 * (KDIM / 4) + aseg;

    // ---- B staging (gload_lds, pre-swizzled source) ----
    const int srow = l >> 3;
    const int sseg = (l & 7) ^ srow;
    const unsigned short* gb[4];
    int ldso[4];
#pragma unroll
    for (int is = 0; is < 4; ++is) {
        int row  = w * 32 + is * 8 + srow;
        int wrow = (row >> 6) * 512 + cb * 64 + (row & 63);
        gb[is]   = W + (size_t)wrow * KDIM + sseg * 8;
        ldso[is] = (w * 32 + is * 8) * BK;
    }

    float4 ra[3][8];
    auto load_a = [&](int kt, int set) {
#pragma unroll
        for (int s = 0; s < 8; ++s)
            ra[set][s] = gA[(size_t)s * 16 * (KDIM / 4) + abase + kt * (BK / 4)];
    };
    auto write_a = [&](int buf, int set) {
#pragma unroll
        for (int s = 0; s < 8; ++s) {
            uint2 o;
            o.x = cvtpk(ra[set][s].x, ra[set][s].y);
            o.y = cvtpk(ra[set][s].z, ra[set][s].w);
            int row = s * 16 + arow0;
            *reinterpret_cast<uint2*>(&At[buf][row * BK + ((aseg * 4) ^ aswz)]) = o;
        }
    };
    auto stage_b = [&](int kt, int buf) {
#pragma unroll
        for (int is = 0; is < 4; ++is)
            gload_lds16(gb[is] + kt * BK, &Bt[buf][ldso[is]]);
    };

    f32x4 acc[4][4];
#pragma unroll
    for (int i = 0; i < 4; ++i)
#pragma unroll
        for (int j = 0; j < 4; ++j) acc[i][j] = f32x4{0.f, 0.f, 0.f, 0.f};

    // ---- prologue: establish steady invariant [A(kt+2):8, B(kt+1):4] ----
    load_a(0, 0);      // A0:8
    load_a(1, 1);      // A1:8
    stage_b(0, 0);     // B0:4
    load_a(2, 2);      // A2:8
    stage_b(1, 1);     // B1:4          FIFO: A0 A1 B0 A2 B1 (32)
    VMCNT(24);         // A0 landed
    write_a(0, 0);
    VMCNT(12);         // A1,B0 landed; remain [A2:8, B1:4] = invariant
    LGKM(0);
    __builtin_amdgcn_s_barrier();

#pragma unroll
    for (int kt = 0; kt < NKT; ++kt) {
        const int buf = kt & 1;

        bf16x8 af[4], bf[4];
        // ks0 fragment reads (slot = l4)
#pragma unroll
        for (int i = 0; i < 4; ++i) {
            int row = wm * 64 + i * 16 + l15;
            af[i] = *(const bf16x8*)(&At[buf][row * BK + (l4 ^ (row & 7)) * 8]);
        }
#pragma unroll
        for (int j = 0; j < 4; ++j) {
            int row = (j >> 1) * 64 + wn * 32 + (j & 1) * 16 + l15;
            bf[j] = *(const bf16x8*)(&Bt[buf][row * BK + (l4 ^ (row & 7)) * 8]);
        }
        // A(kt+1) regs landed (drained by previous iter's vmcnt); convert+write
        if (kt + 1 < NKT) write_a(buf ^ 1, (kt + 1) % 3);
        if (kt + 3 < NKT) load_a(kt + 3, (kt + 3) % 3);

        if (kt + 1 < NKT) { LGKM(8); } else { LGKM(0); }   // ks0 reads retired
        __builtin_amdgcn_sched_barrier(0);
        __builtin_amdgcn_s_setprio(1);
#pragma unroll
        for (int i = 0; i < 4; ++i)
#pragma unroll
            for (int j = 0; j < 4; ++j)
                acc[i][j] = __builtin_amdgcn_mfma_f32_16x16x32_bf16(
                    af[i], bf[j], acc[i][j], 0, 0, 0);
        __builtin_amdgcn_s_setprio(0);

        // ks1 fragment reads (slot = 4 + l4)
#pragma unroll
        for (int i = 0; i < 4; ++i) {
            int row = wm * 64 + i * 16 + l15;
            af[i] = *(const bf16x8*)(&At[buf][row * BK + ((4 + l4) ^ (row & 7)) * 8]);
        }
#pragma unroll
        for (int j = 0; j < 4; ++j) {
            int row = (j >> 1) * 64 + wn * 32 + (j & 1) * 16 + l15;
            bf[j] = *(const bf16x8*)(&Bt[buf][row * BK + ((4 + l4) ^ (row & 7)) * 8]);
        }
        LGKM(0);                                           // all reads + writes done
        __builtin_amdgcn_sched_barrier(0);
        __builtin_amdgcn_s_setprio(1);
#pragma unroll
        for (int i = 0; i < 4; ++i)
#pragma unroll
            for (int j = 0; j < 4; ++j)
                acc[i][j] = __builtin_amdgcn_mfma_f32_16x16x32_bf16(
                    af[i], bf[j], acc[i][j], 0, 0, 0);
        __builtin_amdgcn_s_setprio(0);

        if (kt + 1 < NKT) {
            __builtin_amdgcn_s_barrier();          // all waves done with buf
            // B(kt+1) landed; keep A(kt+3) in flight (tail drains fully)
            if (kt <= 4) { VMCNT(8); } else { VMCNT(0); }
            if (kt + 2 < NKT) stage_b(kt + 2, buf);
            __builtin_amdgcn_s_barrier();          // tile kt+1 visible to all
        }
    }

    // ---- fused modReLU epilogue ----
    // C/D layout (m89): col = lane&15 (n), row = (lane>>4)*4 + j (m)
#pragma unroll
    for (int jn = 0; jn < 2; ++jn) {
        int n = cb * 64 + wn * 32 + jn * 16 + l15;
        float b = bh[n];
#pragma unroll
        for (int i = 0; i < 4; ++i) {
#pragma unroll
            for (int j = 0; j < 4; ++j) {
                int m = mb * BM + wm * 64 + i * 16 + l4 * 4 + j;
                float re  = acc[i][jn][j];
                float imv = acc[i][jn + 2][j];
                float norm  = sqrtf(re * re + imv * imv);
                float scale = fmaxf(norm + b, 0.f) * __builtin_amdgcn_rcpf(norm + 1e-6f);
                float* po = out + (size_t)m * NDIM + n;
                __builtin_nontemporal_store(re  * scale, po);
                __builtin_nontemporal_store(imv * scale, po + 512);
            }
        }
    }
}

extern "C" void kernel_launch(void* const* d_in, const int* in_sizes, int n_in,
                              void* d_out, int out_size, void* d_ws, size_t ws_size,
                              hipStream_t stream) {
    const float* inputs = (const float*)d_in[0];   // (16384, 512) f32
    const float* w_ih   = (const float*)d_in[2];   // (1024, 512)  f32
    const float* b_h    = (const float*)d_in[3];   // (512,)       f32
    float* out = (float*)d_out;                    // (16384, 1024) f32

    unsigned short* Wbf = (unsigned short*)d_ws;   // 1 MiB

    cvt_w<<<256, 256, 0, stream>>>(w_ih, Wbf, (1024 * 512) / 4);

    // 128 m-blocks x 8 col-blocks = 1024 blocks, 2 resident/CU
    gemm_modrelu<<<1024, 256, 0, stream>>>(inputs, Wbf, b_h, out);
}